// Round 1
// baseline (803.432 us; speedup 1.0000x reference)
//
#include <hip/hip_runtime.h>
#include <cmath>

// SpikeFP32GELUExact: [B,S,32] {0,1} fp32 pulse bits -> decode IEEE-754 fp32
// -> exact fp64 tanh-GELU (reference op order) -> fp32 -> re-encode pulses.
//
// Layout: 8 float4s (32 pulses) per value; 8 consecutive lanes cooperate on
// one value via a shfl_xor OR-butterfly (width=8). Fully coalesced 16B/lane
// loads+stores, no LDS. Memory-bound: 1.074 GB total traffic.

__global__ __launch_bounds__(256) void spike_gelu_kernel(
    const float4* __restrict__ in, float4* __restrict__ out, long n4) {
  long f = (long)blockIdx.x * (long)blockDim.x + (long)threadIdx.x;
  if (f >= n4) return;

  float4 p = in[f];

  // g = position of this float4 within its 32-bit value (0..7).
  // Pulse index i maps to bit (31-i): pack 4 pulses into a nibble, place it.
  unsigned g = (unsigned)threadIdx.x & 7u;
  unsigned nib = ((p.x != 0.0f) ? 8u : 0u) | ((p.y != 0.0f) ? 4u : 0u) |
                 ((p.z != 0.0f) ? 2u : 0u) | ((p.w != 0.0f) ? 1u : 0u);
  unsigned s = 28u - 4u * g;
  unsigned u = nib << s;

  // OR-reduce across the aligned 8-lane group: every lane gets the full word.
  u |= __shfl_xor(u, 1, 8);
  u |= __shfl_xor(u, 2, 8);
  u |= __shfl_xor(u, 4, 8);

  float xf = __uint_as_float(u);

  // Exact mirror of the fp64 reference pipeline. Contraction OFF: the
  // reference rounds each mul/add separately; an fma here changes bits.
  double y;
  {
#pragma clang fp contract(off)
    double x = (double)xf;
    double x_cubed = (x * x) * x;
    double inner = x + 0.044715 * x_cubed;
    double two_z = 2.0 * (0.7978845608028654 * inner);
    double e = exp(two_z);
    double th = (e - 1.0) / (e + 1.0);
    y = 0.5 * (x * (1.0 + th));
  }
  float yf = (float)y;

  // Re-encode: this lane writes pulses 4g..4g+3 = bits (31-4g)..(28-4g).
  unsigned r = __float_as_uint(yf);
  float4 o;
  o.x = (float)((r >> (s + 3u)) & 1u);
  o.y = (float)((r >> (s + 2u)) & 1u);
  o.z = (float)((r >> (s + 1u)) & 1u);
  o.w = (float)((r >> s) & 1u);
  out[f] = o;
}

extern "C" void kernel_launch(void* const* d_in, const int* in_sizes, int n_in,
                              void* d_out, int out_size, void* d_ws, size_t ws_size,
                              hipStream_t stream) {
  const float4* in = (const float4*)d_in[0];
  float4* out = (float4*)d_out;
  long n4 = (long)in_sizes[0] / 4;  // 33,554,432 float4s
  int block = 256;
  long grid = (n4 + block - 1) / block;
  spike_gelu_kernel<<<(int)grid, block, 0, stream>>>(in, out, n4);
}